// Round 2
// baseline (885.571 us; speedup 1.0000x reference)
//
#include <hip/hip_runtime.h>

// Problem constants
#define B_   4
#define N_   2048
#define D_   2048
#define H_   16
#define KVH_ 4
#define DH_  128
#define SCALE_ 0.08838834764831845f

typedef __bf16 bf16x8 __attribute__((ext_vector_type(8)));
typedef float  f32x4  __attribute__((ext_vector_type(4)));
typedef unsigned short ushort_t;

typedef __attribute__((address_space(1))) const void* gas_cp;
typedef __attribute__((address_space(3))) void* las_p;

__device__ __forceinline__ void gload_lds16(const void* g, void* l) {
  __builtin_amdgcn_global_load_lds((gas_cp)g, (las_p)l, 16, 0, 0);
}

__device__ __forceinline__ ushort_t f2bf(float f) {
  union { float f; unsigned u; } c;
  c.f = f;
  unsigned u = c.u;
  u += 0x7fffu + ((u >> 16) & 1u);
  return (ushort_t)(u >> 16);
}

__device__ __forceinline__ float bf2f(ushort_t u) {
  union { unsigned u; float f; } c;
  c.u = ((unsigned)u) << 16;
  return c.f;
}

// ---------------- f32 -> bf16 elementwise ----------------
__global__ __launch_bounds__(256) void cvt_f32_bf16_k(
    const float* __restrict__ in, ushort_t* __restrict__ out, int n) {
  int i = (blockIdx.x * 256 + threadIdx.x) * 4;
  if (i >= n) return;
  float4 v = *reinterpret_cast<const float4*>(in + i);
  ushort4 o;
  o.x = f2bf(v.x); o.y = f2bf(v.y); o.z = f2bf(v.z); o.w = f2bf(v.w);
  *reinterpret_cast<ushort4*>(out + i) = o;
}

// ---------------- transpose + convert: src KxN f32 -> dst NxK bf16 ----------------
__global__ __launch_bounds__(256) void tconv_k(
    const float* __restrict__ src, ushort_t* __restrict__ dst, int K, int N) {
  __shared__ float tile[32][33];
  int n0 = blockIdx.x * 32, k0 = blockIdx.y * 32;
  int tx = threadIdx.x, ty = threadIdx.y;
#pragma unroll
  for (int i = 0; i < 32; i += 8)
    tile[ty + i][tx] = src[(size_t)(k0 + ty + i) * N + n0 + tx];
  __syncthreads();
#pragma unroll
  for (int i = 0; i < 32; i += 8)
    dst[(size_t)(n0 + ty + i) * K + k0 + tx] = f2bf(tile[tx][ty + i]);
}

// ---------------- bf16 transpose of V part of qkv: -> vtg[(b*4+kvh)*128+d][n] ----
__global__ __launch_bounds__(256) void vt_k(
    const ushort_t* __restrict__ qkv, ushort_t* __restrict__ vtg) {
  __shared__ ushort_t tile[32][33];
  int n0 = blockIdx.x * 32, d0 = blockIdx.y * 32, g = blockIdx.z;
  int b = g >> 2, kvh = g & 3;
  int tx = threadIdx.x, ty = threadIdx.y;
  const ushort_t* src = qkv + (size_t)(b * N_) * 3072 + 2560 + kvh * 128;
#pragma unroll
  for (int i = 0; i < 32; i += 8)
    tile[ty + i][tx] = src[(size_t)(n0 + ty + i) * 3072 + d0 + tx];
  __syncthreads();
  ushort_t* dst = vtg + (size_t)(g * 128) * 2048;
#pragma unroll
  for (int i = 0; i < 32; i += 8)
    dst[(size_t)(d0 + ty + i) * 2048 + n0 + tx] = tile[tx][ty + i];
}

// ---------------- bf16 GEMM: C = A(MxK) * Bt(NxK)^T, m97 structure + XOR swizzle ----
template <int OUTF32>
__global__ __launch_bounds__(256, 2) void gemm_bt_k(
    const ushort_t* __restrict__ A, const ushort_t* __restrict__ Bt,
    void* __restrict__ C, int M, int N, int K) {
  __shared__ ushort_t As[128 * 64];
  __shared__ ushort_t Bs[128 * 64];
  const int tid = threadIdx.x;
  const int wave = tid >> 6, lane = tid & 63;
  const int lo = lane & 15, hi = lane >> 4;
  const int wm = wave >> 1, wn = wave & 1;
  const int m0 = blockIdx.y * 128, n0 = blockIdx.x * 128;

  f32x4 acc[4][4] = {};

  const int sr = lane >> 3;   // row within 8-row staging group
  const int sc = lane & 7;    // 16B chunk within row

  const int kTiles = K >> 6;
  for (int kt = 0; kt < kTiles; ++kt) {
    const int k0 = kt << 6;
    __syncthreads();
#pragma unroll
    for (int j = 0; j < 4; ++j) {
      int r = wave * 32 + j * 8 + sr;
      int cs = sc ^ (r & 7);
      gload_lds16(A  + (size_t)(m0 + r) * K + k0 + cs * 8, As + (wave * 32 + j * 8) * 64);
      gload_lds16(Bt + (size_t)(n0 + r) * K + k0 + cs * 8, Bs + (wave * 32 + j * 8) * 64);
    }
    __syncthreads();
#pragma unroll
    for (int ks = 0; ks < 2; ++ks) {
      bf16x8 af[4], bfr[4];
#pragma unroll
      for (int mi = 0; mi < 4; ++mi) {
        int r = wm * 64 + mi * 16 + lo;
        int cs = ((ks << 2) | hi) ^ (r & 7);
        af[mi] = *reinterpret_cast<const bf16x8*>(As + r * 64 + cs * 8);
      }
#pragma unroll
      for (int ni = 0; ni < 4; ++ni) {
        int r = wn * 64 + ni * 16 + lo;
        int cs = ((ks << 2) | hi) ^ (r & 7);
        bfr[ni] = *reinterpret_cast<const bf16x8*>(Bs + r * 64 + cs * 8);
      }
#pragma unroll
      for (int mi = 0; mi < 4; ++mi)
#pragma unroll
        for (int ni = 0; ni < 4; ++ni)
          acc[mi][ni] = __builtin_amdgcn_mfma_f32_16x16x32_bf16(af[mi], bfr[ni], acc[mi][ni], 0, 0, 0);
    }
  }
#pragma unroll
  for (int mi = 0; mi < 4; ++mi) {
#pragma unroll
    for (int ni = 0; ni < 4; ++ni) {
#pragma unroll
      for (int r = 0; r < 4; ++r) {
        int row = m0 + wm * 64 + mi * 16 + hi * 4 + r;
        int col = n0 + wn * 64 + ni * 16 + lo;
        float v = acc[mi][ni][r];
        if (OUTF32) reinterpret_cast<float*>(C)[(size_t)row * N + col] = v;
        else        reinterpret_cast<ushort_t*>(C)[(size_t)row * N + col] = f2bf(v);
      }
    }
  }
}

// ---------------- causal GQA flash attention ----------------
// qkv: (B*N) x 3072 bf16 rows = [Q(2048) | K(512) | V(512)]
// vtg: V^T, rows (b*4+kvh)*128+d, length 2048 (tokens)
// ob : (B*N) x 2048 bf16 (merged heads)
// Block: 4 waves, 128 q-rows (32/wave). KV tile = 64.
__global__ __launch_bounds__(256, 3) void attn_k(
    const ushort_t* __restrict__ qkv, const ushort_t* __restrict__ vtg,
    ushort_t* __restrict__ ob) {
  __shared__ ushort_t Ks[64 * 128];   // [kv][d], chunks(8elem) XOR-swizzled by kv&7
  __shared__ ushort_t Vs[128 * 64];   // [d][kv], chunks XOR-swizzled by d&7
  __shared__ ushort_t Pl[4][32 * 72]; // per-wave P [q_local][kv], stride 72

  const int nqb = gridDim.x - 1 - blockIdx.x;   // heaviest blocks first
  const int bh = blockIdx.y;
  const int b = bh >> 4, h = bh & 15, kvh = h & 3;  // jnp.tile => kv head = h % KVH
  const int tid = threadIdx.x, wave = tid >> 6, lane = tid & 63;
  const int lo = lane & 15, hi = lane >> 4;
  const int q0b = nqb * 128;
  const int q0w = q0b + wave * 32;

  const ushort_t* qbase = qkv + (size_t)(b * N_) * 3072;
  const ushort_t* vbase = vtg + (size_t)((b * 4 + kvh) * 128) * 2048;

  // Q fragments x SCALE: qf[mi][kf], row = q0w + mi*16 + lo, d = kf*32 + hi*8 + j
  bf16x8 qf[2][4];
#pragma unroll
  for (int mi = 0; mi < 2; ++mi) {
    const ushort_t* qrow = qbase + (size_t)(q0w + mi * 16 + lo) * 3072 + h * 128;
#pragma unroll
    for (int kf = 0; kf < 4; ++kf) {
      union { bf16x8 v; ushort_t s[8]; } t;
      t.v = *reinterpret_cast<const bf16x8*>(qrow + kf * 32 + hi * 8);
#pragma unroll
      for (int j = 0; j < 8; ++j) t.s[j] = f2bf(bf2f(t.s[j]) * SCALE_);
      qf[mi][kf] = t.v;
    }
  }

  float m[2][4], l[2][4];
#pragma unroll
  for (int mi = 0; mi < 2; ++mi)
#pragma unroll
    for (int r = 0; r < 4; ++r) { m[mi][r] = -3.0e38f; l[mi][r] = 0.f; }
  f32x4 o[2][8] = {};

  const int nk = (nqb + 1) * 2;
  for (int kt = 0; kt < nk; ++kt) {
    const int k0 = kt * 64;
    __syncthreads();
    // stage K tile (64x128): 1024 chunks of 16B, 4 rounds
#pragma unroll
    for (int j = 0; j < 4; ++j) {
      int ci = j * 256 + tid;
      int r = ci >> 4, c = ci & 15;
      int cs = c ^ (r & 7);
      gload_lds16(qbase + (size_t)(k0 + r) * 3072 + 2048 + kvh * 128 + cs * 8,
                  Ks + (size_t)(j * 256 + wave * 64) * 8);
    }
    // stage V^T tile (128x64): 1024 chunks, 4 rounds
#pragma unroll
    for (int j = 0; j < 4; ++j) {
      int ci = j * 256 + tid;
      int r = ci >> 3, c = ci & 7;
      int cs = c ^ (r & 7);
      gload_lds16(vbase + (size_t)r * 2048 + k0 + cs * 8,
                  Vs + (size_t)(j * 256 + wave * 64) * 8);
    }
    __syncthreads();

    if (k0 < q0w + 32) {
      // S = Q K^T : s[mi][cf], rows q_local = mi*16+hi*4+r, cols kv = cf*16+lo
      f32x4 s[2][4] = {};
#pragma unroll
      for (int cf = 0; cf < 4; ++cf) {
        int r = cf * 16 + lo;
        bf16x8 kb[4];
#pragma unroll
        for (int kf = 0; kf < 4; ++kf) {
          int cc = ((kf << 2) | hi) ^ (r & 7);
          kb[kf] = *reinterpret_cast<const bf16x8*>(Ks + r * 128 + cc * 8);
        }
#pragma unroll
        for (int mi = 0; mi < 2; ++mi)
#pragma unroll
          for (int kf = 0; kf < 4; ++kf)
            s[mi][cf] = __builtin_amdgcn_mfma_f32_16x16x32_bf16(qf[mi][kf], kb[kf], s[mi][cf], 0, 0, 0);
      }
      // online softmax (scale pre-folded into Q)
      const bool domask = (k0 + 63 > q0w);
#pragma unroll
      for (int mi = 0; mi < 2; ++mi) {
#pragma unroll
        for (int r = 0; r < 4; ++r) {
          int qrow = q0w + mi * 16 + hi * 4 + r;
          float a[4];
#pragma unroll
          for (int cf = 0; cf < 4; ++cf) a[cf] = s[mi][cf][r];
          if (domask) {
#pragma unroll
            for (int cf = 0; cf < 4; ++cf)
              if (k0 + cf * 16 + lo > qrow) a[cf] = -3.0e38f;
          }
          float mx = fmaxf(fmaxf(a[0], a[1]), fmaxf(a[2], a[3]));
#pragma unroll
          for (int off = 1; off < 16; off <<= 1)
            mx = fmaxf(mx, __shfl_xor(mx, off, 16));
          float mn = fmaxf(m[mi][r], mx);
          float sc = __expf(m[mi][r] - mn);
          m[mi][r] = mn;
          float p[4], ps = 0.f;
#pragma unroll
          for (int cf = 0; cf < 4; ++cf) { p[cf] = __expf(a[cf] - mn); ps += p[cf]; }
#pragma unroll
          for (int off = 1; off < 16; off <<= 1)
            ps += __shfl_xor(ps, off, 16);
          l[mi][r] = l[mi][r] * sc + ps;
#pragma unroll
          for (int f = 0; f < 8; ++f) o[mi][f][r] *= sc;
          int pr = mi * 16 + hi * 4 + r;
#pragma unroll
          for (int cf = 0; cf < 4; ++cf)
            Pl[wave][pr * 72 + cf * 16 + lo] = f2bf(p[cf]);
        }
      }
      // O += P V : A-frag from Pl (row q_local=mi*16+lo), B-frag from Vs (row d=f*16+lo)
      bf16x8 pa[2][2];
#pragma unroll
      for (int mi = 0; mi < 2; ++mi)
#pragma unroll
        for (int ks = 0; ks < 2; ++ks)
          pa[mi][ks] = *reinterpret_cast<const bf16x8*>(&Pl[wave][(mi * 16 + lo) * 72 + ks * 32 + hi * 8]);
#pragma unroll
      for (int f = 0; f < 8; ++f) {
        int r = f * 16 + lo;
#pragma unroll
        for (int ks = 0; ks < 2; ++ks) {
          int cc = (((ks << 2) | hi)) ^ (r & 7);
          bf16x8 vb = *reinterpret_cast<const bf16x8*>(Vs + r * 64 + cc * 8);
#pragma unroll
          for (int mi = 0; mi < 2; ++mi)
            o[mi][f] = __builtin_amdgcn_mfma_f32_16x16x32_bf16(pa[mi][ks], vb, o[mi][f], 0, 0, 0);
        }
      }
    }
  }
  // epilogue
  float inv[2][4];
#pragma unroll
  for (int mi = 0; mi < 2; ++mi)
#pragma unroll
    for (int r = 0; r < 4; ++r) inv[mi][r] = 1.0f / l[mi][r];
  ushort_t* obase = ob + (size_t)(b * N_ + q0w) * 2048 + h * 128;
#pragma unroll
  for (int mi = 0; mi < 2; ++mi)
#pragma unroll
    for (int f = 0; f < 8; ++f)
#pragma unroll
      for (int r = 0; r < 4; ++r)
        obase[(size_t)(mi * 16 + hi * 4 + r) * 2048 + f * 16 + lo] = f2bf(o[mi][f][r] * inv[mi][r]);
}

extern "C" void kernel_launch(void* const* d_in, const int* in_sizes, int n_in,
                              void* d_out, int out_size, void* d_ws, size_t ws_size,
                              hipStream_t stream) {
  const float* x  = (const float*)d_in[0];
  const float* Wq = (const float*)d_in[1];
  const float* Wk = (const float*)d_in[2];
  const float* Wv = (const float*)d_in[3];
  const float* Wo = (const float*)d_in[4];
  float* out = (float*)d_out;

  // ws layout (bf16 elements). obuf aliases xb (dead after GEMM1);
  // vtg aliases w1t (dead after GEMM1, 4.2M <= 6.3M elems).
  ushort_t* xb   = (ushort_t*)d_ws;          // 8192*2048  = 16,777,216
  ushort_t* w1t  = xb  + 16777216;           // 3072*2048  =  6,291,456 (Wq^T|Wk^T|Wv^T)
  ushort_t* wot  = w1t + 6291456;            // 2048*2048  =  4,194,304
  ushort_t* qkv  = wot + 4194304;            // 8192*3072  = 25,165,824
  ushort_t* obuf = xb;                       // alias
  ushort_t* vtg  = w1t;                      // alias: 16*128*2048 = 4,194,304

  cvt_f32_bf16_k<<<16384, 256, 0, stream>>>(x, xb, 16777216);
  dim3 tb(32, 8);
  tconv_k<<<dim3(64, 64), tb, 0, stream>>>(Wq, w1t,               2048, 2048);
  tconv_k<<<dim3(16, 64), tb, 0, stream>>>(Wk, w1t + 2048 * 2048, 2048, 512);
  tconv_k<<<dim3(16, 64), tb, 0, stream>>>(Wv, w1t + 2560 * 2048, 2048, 512);
  tconv_k<<<dim3(64, 64), tb, 0, stream>>>(Wo, wot,               2048, 2048);

  // QKV projection: (8192 x 2048) * (3072 x 2048)^T -> bf16 qkv
  gemm_bt_k<0><<<dim3(24, 64), 256, 0, stream>>>(xb, w1t, qkv, 8192, 3072, 2048);
  // V^T for attention (w1t dead now)
  vt_k<<<dim3(64, 4, 16), tb, 0, stream>>>(qkv, vtg);
  // causal GQA flash attention
  attn_k<<<dim3(16, 64), 256, 0, stream>>>(qkv, vtg, obuf);
  // output projection: (8192 x 2048) * (2048 x 2048)^T -> f32 out
  gemm_bt_k<1><<<dim3(16, 64), 256, 0, stream>>>(obuf, wot, out, 8192, 2048, 2048);
}

// Round 4
// 558.920 us; speedup vs baseline: 1.5844x; 1.5844x over previous
//
#include <hip/hip_runtime.h>

// Problem constants
#define B_   4
#define N_   2048
#define D_   2048
#define H_   16
#define KVH_ 4
#define DH_  128
#define SCALE_ 0.08838834764831845f
#define NEGF_ (-1.0e30f)

typedef __bf16 bf16x8 __attribute__((ext_vector_type(8)));
typedef float  f32x4  __attribute__((ext_vector_type(4)));
typedef unsigned short ushort_t;

typedef __attribute__((address_space(1))) const void* gas_cp;
typedef __attribute__((address_space(3))) void* las_p;

__device__ __forceinline__ void gload_lds16(const void* g, void* l) {
  __builtin_amdgcn_global_load_lds((gas_cp)g, (las_p)l, 16, 0, 0);
}

__device__ __forceinline__ ushort_t f2bf(float f) {
  union { float f; unsigned u; } c;
  c.f = f;
  unsigned u = c.u;
  u += 0x7fffu + ((u >> 16) & 1u);
  return (ushort_t)(u >> 16);
}

__device__ __forceinline__ float bf2f(ushort_t u) {
  union { unsigned u; float f; } c;
  c.u = ((unsigned)u) << 16;
  return c.f;
}

// ---------------- f32 -> bf16 elementwise ----------------
__global__ __launch_bounds__(256) void cvt_f32_bf16_k(
    const float* __restrict__ in, ushort_t* __restrict__ out, int n) {
  int i = (blockIdx.x * 256 + threadIdx.x) * 4;
  if (i >= n) return;
  float4 v = *reinterpret_cast<const float4*>(in + i);
  ushort4 o;
  o.x = f2bf(v.x); o.y = f2bf(v.y); o.z = f2bf(v.z); o.w = f2bf(v.w);
  *reinterpret_cast<ushort4*>(out + i) = o;
}

// ---------------- transpose + convert: src KxN f32 -> dst NxK bf16 ----------------
__global__ __launch_bounds__(256) void tconv_k(
    const float* __restrict__ src, ushort_t* __restrict__ dst, int K, int N) {
  __shared__ float tile[32][33];
  int n0 = blockIdx.x * 32, k0 = blockIdx.y * 32;
  int tx = threadIdx.x, ty = threadIdx.y;
#pragma unroll
  for (int i = 0; i < 32; i += 8)
    tile[ty + i][tx] = src[(size_t)(k0 + ty + i) * N + n0 + tx];
  __syncthreads();
#pragma unroll
  for (int i = 0; i < 32; i += 8)
    dst[(size_t)(n0 + ty + i) * K + k0 + tx] = f2bf(tile[tx][ty + i]);
}

// ---------------- bf16 transpose of V part of qkv: -> vtg[(b*4+kvh)*128+d][n] ----
__global__ __launch_bounds__(256) void vt_k(
    const ushort_t* __restrict__ qkv, ushort_t* __restrict__ vtg) {
  __shared__ ushort_t tile[32][33];
  int n0 = blockIdx.x * 32, d0 = blockIdx.y * 32, g = blockIdx.z;
  int b = g >> 2, kvh = g & 3;
  int tx = threadIdx.x, ty = threadIdx.y;
  const ushort_t* src = qkv + (size_t)(b * N_) * 3072 + 2560 + kvh * 128;
#pragma unroll
  for (int i = 0; i < 32; i += 8)
    tile[ty + i][tx] = src[(size_t)(n0 + ty + i) * 3072 + d0 + tx];
  __syncthreads();
  ushort_t* dst = vtg + (size_t)(g * 128) * 2048;
#pragma unroll
  for (int i = 0; i < 32; i += 8)
    dst[(size_t)(d0 + ty + i) * 2048 + n0 + tx] = tile[tx][ty + i];
}

// ---------------- bf16 GEMM: C = A(MxK) * Bt(NxK)^T, m97 structure + XOR swizzle ----
template <int OUTF32>
__global__ __launch_bounds__(256, 2) void gemm_bt_k(
    const ushort_t* __restrict__ A, const ushort_t* __restrict__ Bt,
    void* __restrict__ C, int M, int N, int K) {
  __shared__ ushort_t As[128 * 64];
  __shared__ ushort_t Bs[128 * 64];
  const int tid = threadIdx.x;
  const int wave = tid >> 6, lane = tid & 63;
  const int lo = lane & 15, hi = lane >> 4;
  const int wm = wave >> 1, wn = wave & 1;
  // bijective XCD swizzle (nwg % 8 == 0 for all our launches)
  const int nwg = gridDim.x * gridDim.y;
  const int id = blockIdx.y * gridDim.x + blockIdx.x;
  const int swz = (id & 7) * (nwg >> 3) + (id >> 3);
  const int m0 = (swz / gridDim.x) * 128, n0 = (swz % gridDim.x) * 128;

  f32x4 acc[4][4] = {};

  const int sr = lane >> 3;   // row within 8-row staging group
  const int sc = lane & 7;    // 16B chunk within row

  const int kTiles = K >> 6;
  for (int kt = 0; kt < kTiles; ++kt) {
    const int k0 = kt << 6;
    __syncthreads();
#pragma unroll
    for (int j = 0; j < 4; ++j) {
      int r = wave * 32 + j * 8 + sr;
      int cs = sc ^ (r & 7);
      gload_lds16(A  + (size_t)(m0 + r) * K + k0 + cs * 8, As + (wave * 32 + j * 8) * 64);
      gload_lds16(Bt + (size_t)(n0 + r) * K + k0 + cs * 8, Bs + (wave * 32 + j * 8) * 64);
    }
    __syncthreads();
#pragma unroll
    for (int ks = 0; ks < 2; ++ks) {
      bf16x8 af[4], bfr[4];
#pragma unroll
      for (int mi = 0; mi < 4; ++mi) {
        int r = wm * 64 + mi * 16 + lo;
        int cs = ((ks << 2) | hi) ^ (r & 7);
        af[mi] = *reinterpret_cast<const bf16x8*>(As + r * 64 + cs * 8);
      }
#pragma unroll
      for (int ni = 0; ni < 4; ++ni) {
        int r = wn * 64 + ni * 16 + lo;
        int cs = ((ks << 2) | hi) ^ (r & 7);
        bfr[ni] = *reinterpret_cast<const bf16x8*>(Bs + r * 64 + cs * 8);
      }
#pragma unroll
      for (int mi = 0; mi < 4; ++mi)
#pragma unroll
        for (int ni = 0; ni < 4; ++ni)
          acc[mi][ni] = __builtin_amdgcn_mfma_f32_16x16x32_bf16(af[mi], bfr[ni], acc[mi][ni], 0, 0, 0);
    }
  }
#pragma unroll
  for (int mi = 0; mi < 4; ++mi) {
#pragma unroll
    for (int ni = 0; ni < 4; ++ni) {
#pragma unroll
      for (int r = 0; r < 4; ++r) {
        int row = m0 + wm * 64 + mi * 16 + hi * 4 + r;
        int col = n0 + wn * 64 + ni * 16 + lo;
        float v = acc[mi][ni][r];
        if (OUTF32) reinterpret_cast<float*>(C)[(size_t)row * N + col] = v;
        else        reinterpret_cast<ushort_t*>(C)[(size_t)row * N + col] = f2bf(v);
      }
    }
  }
}

// ---------------- causal GQA flash attention (swapped QK^T + 2-phase pipeline) ----
// qkv: (B*N) x 3072 bf16 rows = [Q(2048) | K(512) | V(512)]
// vtg: V^T, rows (b*4+kvh)*128+d, length 2048 (tokens)
// ob : (B*N) x 2048 bf16 (merged heads)
// Block: 4 waves, 128 q-rows (32/wave). KV tile = 64, double-buffered.
__global__ __launch_bounds__(256, 2) void attn_k(
    const ushort_t* __restrict__ qkv, const ushort_t* __restrict__ vtg,
    ushort_t* __restrict__ ob) {
  __shared__ ushort_t Ks[2][64 * 128];  // [kv][d] chunks(8) XOR-swizzled by kv&7
  __shared__ ushort_t Vs[2][128 * 64];  // [d][kv] chunks XOR-swizzled by d&7
  __shared__ ushort_t Pl[4][32 * 40];   // per-wave P [q32][kv_half 32 + pad 8]

  const int nqb = gridDim.x - 1 - blockIdx.x;   // heaviest blocks first
  const int bh = blockIdx.y;
  const int b = bh >> 4, h = bh & 15, kvh = h & 3;  // jnp.tile => kv head = h % KVH
  const int tid = threadIdx.x, wave = tid >> 6, lane = tid & 63;
  const int lo = lane & 15, hi = lane >> 4;
  const int q0w = nqb * 128 + wave * 32;

  const ushort_t* qbase = qkv + (size_t)(b * N_) * 3072;
  const ushort_t* kbase = qbase + 2048 + kvh * 128;
  const ushort_t* vbase = vtg + (size_t)((b * 4 + kvh) * 128) * 2048;

  // Q fragments x SCALE: qf[mi][kf], q-row = q0w+mi*16+lo, d=kf*32+hi*8+j
  bf16x8 qf[2][4];
#pragma unroll
  for (int mi = 0; mi < 2; ++mi) {
    const ushort_t* qrow = qbase + (size_t)(q0w + mi * 16 + lo) * 3072 + h * 128;
#pragma unroll
    for (int kf = 0; kf < 4; ++kf) {
      union { bf16x8 v; ushort_t s[8]; } t;
      t.v = *reinterpret_cast<const bf16x8*>(qrow + kf * 32 + hi * 8);
#pragma unroll
      for (int j = 0; j < 8; ++j) t.s[j] = f2bf(bf2f(t.s[j]) * SCALE_);
      qf[mi][kf] = t.v;
    }
  }

  float m[2] = {NEGF_, NEGF_};
  float l[2] = {0.f, 0.f};
  f32x4 o[2][8] = {};

  const int nk = (nqb + 1) * 2;

  auto STAGE = [&](int k0, int bufi) {
#pragma unroll
    for (int j = 0; j < 4; ++j) {
      int ci = j * 256 + tid;
      int r = ci >> 4, c = ci & 15;
      gload_lds16(kbase + (size_t)(k0 + r) * 3072 + (c ^ (r & 7)) * 8,
                  &Ks[bufi][(j * 256 + wave * 64) * 8]);
    }
#pragma unroll
    for (int j = 0; j < 4; ++j) {
      int ci = j * 256 + tid;
      int r = ci >> 3, c = ci & 7;
      gload_lds16(vbase + (size_t)r * 2048 + k0 + (c ^ (r & 7)) * 8,
                  &Vs[bufi][(j * 256 + wave * 64) * 8]);
    }
  };

  STAGE(0, 0);
  __syncthreads();
  int cur = 0;

  for (int kt = 0; kt < nk; ++kt) {
    const int k0 = kt * 64;
    if (kt + 1 < nk) STAGE(k0 + 64, cur ^ 1);   // prefetch next tile (in flight)

    const bool act = (k0 < q0w + 32);           // wave-uniform
    if (act) {
      // S^T = K Q^T : s[mi][cf][r] = S[kv=k0+cf*16+hi*4+r][q=q0w+mi*16+lo]
      f32x4 s[2][4] = {};
#pragma unroll
      for (int cf = 0; cf < 4; ++cf) {
        int r = cf * 16 + lo;
        bf16x8 kb[4];
#pragma unroll
        for (int kf = 0; kf < 4; ++kf) {
          int cc = ((kf << 2) | hi) ^ (r & 7);
          kb[kf] = *reinterpret_cast<const bf16x8*>(&Ks[cur][r * 128 + cc * 8]);
        }
#pragma unroll
        for (int mi = 0; mi < 2; ++mi)
#pragma unroll
          for (int kf = 0; kf < 4; ++kf)
            s[mi][cf] = __builtin_amdgcn_mfma_f32_16x16x32_bf16(kb[kf], qf[mi][kf], s[mi][cf], 0, 0, 0);
      }
      // online softmax: lane owns q-row q0w+mi*16+lo; 16 kv values in regs
#pragma unroll
      for (int mi = 0; mi < 2; ++mi) {
        const int qrow = q0w + mi * 16 + lo;
        const bool domask = (k0 + 63 > q0w + mi * 16);   // wave-uniform, exact per-elem below
        float mx = NEGF_;
#pragma unroll
        for (int cf = 0; cf < 4; ++cf)
#pragma unroll
          for (int r = 0; r < 4; ++r) {
            float v = s[mi][cf][r];
            if (domask && (k0 + cf * 16 + hi * 4 + r > qrow)) v = NEGF_;
            s[mi][cf][r] = v;
            mx = fmaxf(mx, v);
          }
        mx = fmaxf(mx, __shfl_xor(mx, 16, 64));
        mx = fmaxf(mx, __shfl_xor(mx, 32, 64));
        float mn = fmaxf(m[mi], mx);
        float sc = __expf(m[mi] - mn);
        m[mi] = mn;
        float ps = 0.f;
#pragma unroll
        for (int cf = 0; cf < 4; ++cf)
#pragma unroll
          for (int r = 0; r < 4; ++r) {
            float p = __expf(s[mi][cf][r] - mn);
            ps += p;
            s[mi][cf][r] = p;
          }
        ps += __shfl_xor(ps, 16, 64);
        ps += __shfl_xor(ps, 32, 64);
        l[mi] = l[mi] * sc + ps;
        // broadcast sc to O-layout lanes (dest lane needs sc of q_local=hi*4+r)
        int bsrc = (lane & 48) | (hi << 2);
#pragma unroll
        for (int r = 0; r < 4; ++r) {
          float sb = __shfl(sc, bsrc + r, 64);
#pragma unroll
          for (int f = 0; f < 8; ++f) o[mi][f][r] *= sb;
        }
      }
      // O += P V in two kv-half phases; Pl holds one 32-wide half at a time.
#pragma unroll
      for (int ks = 0; ks < 2; ++ks) {
#pragma unroll
        for (int mi = 0; mi < 2; ++mi)
#pragma unroll
          for (int c2 = 0; c2 < 2; ++c2) {
            int cf = ks * 2 + c2;
            unsigned w0 = (unsigned)f2bf(s[mi][cf][0]) | ((unsigned)f2bf(s[mi][cf][1]) << 16);
            unsigned w1 = (unsigned)f2bf(s[mi][cf][2]) | ((unsigned)f2bf(s[mi][cf][3]) << 16);
            uint2 w; w.x = w0; w.y = w1;
            *reinterpret_cast<uint2*>(&Pl[wave][(mi * 16 + lo) * 40 + c2 * 16 + hi * 4]) = w;
          }
        bf16x8 pa[2];
#pragma unroll
        for (int mi = 0; mi < 2; ++mi)
          pa[mi] = *reinterpret_cast<const bf16x8*>(&Pl[wave][(mi * 16 + lo) * 40 + hi * 8]);
#pragma unroll
        for (int f = 0; f < 8; ++f) {
          int d = f * 16 + lo;
          int cc = ((ks << 2) | hi) ^ (d & 7);
          bf16x8 vb = *reinterpret_cast<const bf16x8*>(&Vs[cur][d * 64 + cc * 8]);
#pragma unroll
          for (int mi = 0; mi < 2; ++mi)
            o[mi][f] = __builtin_amdgcn_mfma_f32_16x16x32_bf16(pa[mi], vb, o[mi][f], 0, 0, 0);
        }
      }
    }
    __syncthreads();   // drains prefetch vmcnt + guards buffer reuse
    cur ^= 1;
  }

  // epilogue: normalize (broadcast 1/l to O-layout) and store merged heads
  ushort_t* obase = ob + (size_t)(b * N_ + q0w) * 2048 + h * 128;
#pragma unroll
  for (int mi = 0; mi < 2; ++mi) {
    float invl = 1.0f / l[mi];
    int bsrc = (lane & 48) | (hi << 2);
    float ib[4];
#pragma unroll
    for (int r = 0; r < 4; ++r) ib[r] = __shfl(invl, bsrc + r, 64);
#pragma unroll
    for (int f = 0; f < 8; ++f)
#pragma unroll
      for (int r = 0; r < 4; ++r)
        obase[(size_t)(mi * 16 + hi * 4 + r) * 2048 + f * 16 + lo] = f2bf(o[mi][f][r] * ib[r]);
  }
}

extern "C" void kernel_launch(void* const* d_in, const int* in_sizes, int n_in,
                              void* d_out, int out_size, void* d_ws, size_t ws_size,
                              hipStream_t stream) {
  const float* x  = (const float*)d_in[0];
  const float* Wq = (const float*)d_in[1];
  const float* Wk = (const float*)d_in[2];
  const float* Wv = (const float*)d_in[3];
  const float* Wo = (const float*)d_in[4];
  float* out = (float*)d_out;

  // ws layout (bf16 elements). obuf aliases xb (dead after GEMM1);
  // vtg aliases w1t (dead after GEMM1, 4.2M <= 6.3M elems).
  ushort_t* xb   = (ushort_t*)d_ws;          // 8192*2048  = 16,777,216
  ushort_t* w1t  = xb  + 16777216;           // 3072*2048  =  6,291,456 (Wq^T|Wk^T|Wv^T)
  ushort_t* wot  = w1t + 6291456;            // 2048*2048  =  4,194,304
  ushort_t* qkv  = wot + 4194304;            // 8192*3072  = 25,165,824
  ushort_t* obuf = xb;                       // alias
  ushort_t* vtg  = w1t;                      // alias: 16*128*2048 = 4,194,304

  cvt_f32_bf16_k<<<16384, 256, 0, stream>>>(x, xb, 16777216);
  dim3 tb(32, 8);
  tconv_k<<<dim3(64, 64), tb, 0, stream>>>(Wq, w1t,               2048, 2048);
  tconv_k<<<dim3(16, 64), tb, 0, stream>>>(Wk, w1t + 2048 * 2048, 2048, 512);
  tconv_k<<<dim3(16, 64), tb, 0, stream>>>(Wv, w1t + 2560 * 2048, 2048, 512);
  tconv_k<<<dim3(64, 64), tb, 0, stream>>>(Wo, wot,               2048, 2048);

  // QKV projection: (8192 x 2048) * (3072 x 2048)^T -> bf16 qkv
  gemm_bt_k<0><<<dim3(24, 64), 256, 0, stream>>>(xb, w1t, qkv, 8192, 3072, 2048);
  // V^T for attention (w1t dead now)
  vt_k<<<dim3(64, 4, 16), tb, 0, stream>>>(qkv, vtg);
  // causal GQA flash attention
  attn_k<<<dim3(16, 64), 256, 0, stream>>>(qkv, vtg, obuf);
  // output projection: (8192 x 2048) * (2048 x 2048)^T -> f32 out
  gemm_bt_k<1><<<dim3(16, 64), 256, 0, stream>>>(obuf, wot, out, 8192, 2048, 2048);
}

// Round 5
// 447.536 us; speedup vs baseline: 1.9788x; 1.2489x over previous
//
#include <hip/hip_runtime.h>

// Problem constants
#define B_   4
#define N_   2048
#define D_   2048
#define H_   16
#define KVH_ 4
#define DH_  128
#define SCALE_ 0.08838834764831845f
#define NEGF_ (-1.0e30f)

typedef __bf16 bf16x8 __attribute__((ext_vector_type(8)));
typedef float  f32x4  __attribute__((ext_vector_type(4)));
typedef unsigned short ushort_t;

typedef __attribute__((address_space(1))) const void* gas_cp;
typedef __attribute__((address_space(3))) void* las_p;

__device__ __forceinline__ void gload_lds16(const void* g, void* l) {
  __builtin_amdgcn_global_load_lds((gas_cp)g, (las_p)l, 16, 0, 0);
}

__device__ __forceinline__ ushort_t f2bf(float f) {
  union { float f; unsigned u; } c;
  c.f = f;
  unsigned u = c.u;
  u += 0x7fffu + ((u >> 16) & 1u);
  return (ushort_t)(u >> 16);
}

__device__ __forceinline__ float bf2f(ushort_t u) {
  union { unsigned u; float f; } c;
  c.u = ((unsigned)u) << 16;
  return c.f;
}

// ---------------- f32 -> bf16 elementwise ----------------
__global__ __launch_bounds__(256) void cvt_f32_bf16_k(
    const float* __restrict__ in, ushort_t* __restrict__ out, int n) {
  int i = (blockIdx.x * 256 + threadIdx.x) * 4;
  if (i >= n) return;
  float4 v = *reinterpret_cast<const float4*>(in + i);
  ushort4 o;
  o.x = f2bf(v.x); o.y = f2bf(v.y); o.z = f2bf(v.z); o.w = f2bf(v.w);
  *reinterpret_cast<ushort4*>(out + i) = o;
}

// ---------------- transpose + convert: src KxN f32 -> dst NxK bf16 ----------------
__global__ __launch_bounds__(256) void tconv_k(
    const float* __restrict__ src, ushort_t* __restrict__ dst, int K, int N) {
  __shared__ float tile[32][33];
  int n0 = blockIdx.x * 32, k0 = blockIdx.y * 32;
  int tx = threadIdx.x, ty = threadIdx.y;
#pragma unroll
  for (int i = 0; i < 32; i += 8)
    tile[ty + i][tx] = src[(size_t)(k0 + ty + i) * N + n0 + tx];
  __syncthreads();
#pragma unroll
  for (int i = 0; i < 32; i += 8)
    dst[(size_t)(n0 + ty + i) * K + k0 + tx] = f2bf(tile[tx][ty + i]);
}

// ---------------- bf16 transpose of V part of qkv: -> vtg[(b*4+kvh)*128+d][n] ----
__global__ __launch_bounds__(256) void vt_k(
    const ushort_t* __restrict__ qkv, ushort_t* __restrict__ vtg) {
  __shared__ ushort_t tile[32][33];
  int n0 = blockIdx.x * 32, d0 = blockIdx.y * 32, g = blockIdx.z;
  int b = g >> 2, kvh = g & 3;
  int tx = threadIdx.x, ty = threadIdx.y;
  const ushort_t* src = qkv + (size_t)(b * N_) * 3072 + 2560 + kvh * 128;
#pragma unroll
  for (int i = 0; i < 32; i += 8)
    tile[ty + i][tx] = src[(size_t)(n0 + ty + i) * 3072 + d0 + tx];
  __syncthreads();
  ushort_t* dst = vtg + (size_t)(g * 128) * 2048;
#pragma unroll
  for (int i = 0; i < 32; i += 8)
    dst[(size_t)(d0 + ty + i) * 2048 + n0 + tx] = tile[tx][ty + i];
}

// ---------------- bf16 GEMM: C = A(MxK) * Bt(NxK)^T, m97 structure + XOR swizzle ----
template <int OUTF32>
__global__ __launch_bounds__(256, 2) void gemm_bt_k(
    const ushort_t* __restrict__ A, const ushort_t* __restrict__ Bt,
    void* __restrict__ C, int M, int N, int K) {
  __shared__ ushort_t As[128 * 64];
  __shared__ ushort_t Bs[128 * 64];
  const int tid = threadIdx.x;
  const int wave = tid >> 6, lane = tid & 63;
  const int lo = lane & 15, hi = lane >> 4;
  const int wm = wave >> 1, wn = wave & 1;
  // bijective XCD swizzle (nwg % 8 == 0 for all our launches)
  const int nwg = gridDim.x * gridDim.y;
  const int id = blockIdx.y * gridDim.x + blockIdx.x;
  const int swz = (id & 7) * (nwg >> 3) + (id >> 3);
  const int m0 = (swz / gridDim.x) * 128, n0 = (swz % gridDim.x) * 128;

  f32x4 acc[4][4] = {};

  const int sr = lane >> 3;   // row within 8-row staging group
  const int sc = lane & 7;    // 16B chunk within row

  const int kTiles = K >> 6;
  for (int kt = 0; kt < kTiles; ++kt) {
    const int k0 = kt << 6;
    __syncthreads();
#pragma unroll
    for (int j = 0; j < 4; ++j) {
      int r = wave * 32 + j * 8 + sr;
      int cs = sc ^ (r & 7);
      gload_lds16(A  + (size_t)(m0 + r) * K + k0 + cs * 8, As + (wave * 32 + j * 8) * 64);
      gload_lds16(Bt + (size_t)(n0 + r) * K + k0 + cs * 8, Bs + (wave * 32 + j * 8) * 64);
    }
    __syncthreads();
#pragma unroll
    for (int ks = 0; ks < 2; ++ks) {
      bf16x8 af[4], bfr[4];
#pragma unroll
      for (int mi = 0; mi < 4; ++mi) {
        int r = wm * 64 + mi * 16 + lo;
        int cs = ((ks << 2) | hi) ^ (r & 7);
        af[mi] = *reinterpret_cast<const bf16x8*>(As + r * 64 + cs * 8);
      }
#pragma unroll
      for (int ni = 0; ni < 4; ++ni) {
        int r = wn * 64 + ni * 16 + lo;
        int cs = ((ks << 2) | hi) ^ (r & 7);
        bfr[ni] = *reinterpret_cast<const bf16x8*>(Bs + r * 64 + cs * 8);
      }
#pragma unroll
      for (int mi = 0; mi < 4; ++mi)
#pragma unroll
        for (int ni = 0; ni < 4; ++ni)
          acc[mi][ni] = __builtin_amdgcn_mfma_f32_16x16x32_bf16(af[mi], bfr[ni], acc[mi][ni], 0, 0, 0);
    }
  }
#pragma unroll
  for (int mi = 0; mi < 4; ++mi) {
#pragma unroll
    for (int ni = 0; ni < 4; ++ni) {
#pragma unroll
      for (int r = 0; r < 4; ++r) {
        int row = m0 + wm * 64 + mi * 16 + hi * 4 + r;
        int col = n0 + wn * 64 + ni * 16 + lo;
        float v = acc[mi][ni][r];
        if (OUTF32) reinterpret_cast<float*>(C)[(size_t)row * N + col] = v;
        else        reinterpret_cast<ushort_t*>(C)[(size_t)row * N + col] = f2bf(v);
      }
    }
  }
}

// ---------------- causal GQA flash attention (swapped QK^T + 2-phase pipeline) ----
// qkv: (B*N) x 3072 bf16 rows = [Q(2048) | K(512) | V(512)]
// vtg: V^T, rows (b*4+kvh)*128+d, length 2048 (tokens)
// ob : (B*N) x 2048 bf16 (merged heads)
// Block: 4 waves, 32 q-rows/wave. KV tile = 64, double-buffered.
// Each block runs TWO q-tiles (heavy 15-i, then light i) => 512 equal-work blocks.
__global__ __launch_bounds__(256, 2) void attn_k(
    const ushort_t* __restrict__ qkv, const ushort_t* __restrict__ vtg,
    ushort_t* __restrict__ ob) {
  __shared__ ushort_t Ks[2][64 * 128];  // [kv][d] chunks(8) XOR-swizzled by kv&7
  __shared__ ushort_t Vs[2][128 * 64];  // [d][kv] chunks XOR-swizzled by d&7
  __shared__ ushort_t Pl[4][32 * 40];   // per-wave P [q32][kv_half 32 + pad 8]

  const int bh = blockIdx.y;
  const int b = bh >> 4, h = bh & 15, kvh = h & 3;  // jnp.tile => kv head = h % KVH
  const int tid = threadIdx.x, wave = tid >> 6, lane = tid & 63;
  const int lo = lane & 15, hi = lane >> 4;

  const ushort_t* qbase = qkv + (size_t)(b * N_) * 3072;
  const ushort_t* kbase = qbase + 2048 + kvh * 128;
  const ushort_t* vbase = vtg + (size_t)((b * 4 + kvh) * 128) * 2048;

  auto STAGE = [&](int k0, int bufi) {
#pragma unroll
    for (int j = 0; j < 4; ++j) {
      int ci = j * 256 + tid;
      int r = ci >> 4, c = ci & 15;
      gload_lds16(kbase + (size_t)(k0 + r) * 3072 + (c ^ (r & 7)) * 8,
                  &Ks[bufi][(j * 256 + wave * 64) * 8]);
    }
#pragma unroll
    for (int j = 0; j < 4; ++j) {
      int ci = j * 256 + tid;
      int r = ci >> 3, c = ci & 7;
      gload_lds16(vbase + (size_t)r * 2048 + k0 + (c ^ (r & 7)) * 8,
                  &Vs[bufi][(j * 256 + wave * 64) * 8]);
    }
  };

#pragma unroll 1
  for (int pass = 0; pass < 2; ++pass) {
    const int nqb = pass ? blockIdx.x : (15 - blockIdx.x);
    const int q0w = nqb * 128 + wave * 32;

    // Q fragments x SCALE: qf[mi][kf], q-row = q0w+mi*16+lo, d=kf*32+hi*8+j
    bf16x8 qf[2][4];
#pragma unroll
    for (int mi = 0; mi < 2; ++mi) {
      const ushort_t* qrow = qbase + (size_t)(q0w + mi * 16 + lo) * 3072 + h * 128;
#pragma unroll
      for (int kf = 0; kf < 4; ++kf) {
        union { bf16x8 v; ushort_t s[8]; } t;
        t.v = *reinterpret_cast<const bf16x8*>(qrow + kf * 32 + hi * 8);
#pragma unroll
        for (int j = 0; j < 8; ++j) t.s[j] = f2bf(bf2f(t.s[j]) * SCALE_);
        qf[mi][kf] = t.v;
      }
    }

    float m[2] = {NEGF_, NEGF_};
    float l[2] = {0.f, 0.f};
    f32x4 o[2][8] = {};

    const int nk = (nqb + 1) * 2;

    STAGE(0, 0);
    __syncthreads();
    int cur = 0;

    for (int kt = 0; kt < nk; ++kt) {
      const int k0 = kt * 64;
      if (kt + 1 < nk) STAGE(k0 + 64, cur ^ 1);   // prefetch next tile (in flight)

      const bool act = (k0 < q0w + 32);           // wave-uniform
      if (act) {
        // S^T = K Q^T : s[mi][cf][r] = S[kv=k0+cf*16+hi*4+r][q=q0w+mi*16+lo]
        f32x4 s[2][4] = {};
        __builtin_amdgcn_s_setprio(1);
#pragma unroll
        for (int cf = 0; cf < 4; ++cf) {
          int r = cf * 16 + lo;
          bf16x8 kb[4];
#pragma unroll
          for (int kf = 0; kf < 4; ++kf) {
            int cc = ((kf << 2) | hi) ^ (r & 7);
            kb[kf] = *reinterpret_cast<const bf16x8*>(&Ks[cur][r * 128 + cc * 8]);
          }
#pragma unroll
          for (int mi = 0; mi < 2; ++mi)
#pragma unroll
            for (int kf = 0; kf < 4; ++kf)
              s[mi][cf] = __builtin_amdgcn_mfma_f32_16x16x32_bf16(kb[kf], qf[mi][kf], s[mi][cf], 0, 0, 0);
        }
        __builtin_amdgcn_s_setprio(0);
        // online softmax: lane owns q-row q0w+mi*16+lo; 16 kv values in regs
#pragma unroll
        for (int mi = 0; mi < 2; ++mi) {
          const int qrow = q0w + mi * 16 + lo;
          const bool domask = (k0 + 63 > q0w + mi * 16);   // wave-uniform
          float mx = NEGF_;
#pragma unroll
          for (int cf = 0; cf < 4; ++cf)
#pragma unroll
            for (int r = 0; r < 4; ++r) {
              float v = s[mi][cf][r];
              if (domask && (k0 + cf * 16 + hi * 4 + r > qrow)) v = NEGF_;
              s[mi][cf][r] = v;
              mx = fmaxf(mx, v);
            }
          mx = fmaxf(mx, __shfl_xor(mx, 16, 64));
          mx = fmaxf(mx, __shfl_xor(mx, 32, 64));
          // defer-max (T13): skip rescale when tile max stays within threshold
          const bool noresc = __all(mx <= m[mi] + 8.0f);
          float mn, sc;
          if (noresc) {
            mn = m[mi];
          } else {
            mn = fmaxf(m[mi], mx);
            sc = __expf(m[mi] - mn);
            m[mi] = mn;
          }
          float ps = 0.f;
#pragma unroll
          for (int cf = 0; cf < 4; ++cf)
#pragma unroll
            for (int r = 0; r < 4; ++r) {
              float p = __expf(s[mi][cf][r] - mn);
              ps += p;
              s[mi][cf][r] = p;
            }
          ps += __shfl_xor(ps, 16, 64);
          ps += __shfl_xor(ps, 32, 64);
          if (noresc) {
            l[mi] += ps;
          } else {
            l[mi] = l[mi] * sc + ps;
            // broadcast sc to O-layout lanes (dest lane needs sc of q_local=hi*4+r)
            int bsrc = (lane & 48) | (hi << 2);
#pragma unroll
            for (int r = 0; r < 4; ++r) {
              float sb = __shfl(sc, bsrc + r, 64);
#pragma unroll
              for (int f = 0; f < 8; ++f) o[mi][f][r] *= sb;
            }
          }
        }
        // O += P V in two kv-half phases; Pl holds one 32-wide half at a time.
#pragma unroll
        for (int ks = 0; ks < 2; ++ks) {
#pragma unroll
          for (int mi = 0; mi < 2; ++mi)
#pragma unroll
            for (int c2 = 0; c2 < 2; ++c2) {
              int cf = ks * 2 + c2;
              unsigned w0, w1;
              asm("v_cvt_pk_bf16_f32 %0, %1, %2"
                  : "=v"(w0) : "v"(s[mi][cf][0]), "v"(s[mi][cf][1]));
              asm("v_cvt_pk_bf16_f32 %0, %1, %2"
                  : "=v"(w1) : "v"(s[mi][cf][2]), "v"(s[mi][cf][3]));
              uint2 w; w.x = w0; w.y = w1;
              *reinterpret_cast<uint2*>(&Pl[wave][(mi * 16 + lo) * 40 + c2 * 16 + hi * 4]) = w;
            }
          bf16x8 pa[2];
#pragma unroll
          for (int mi = 0; mi < 2; ++mi)
            pa[mi] = *reinterpret_cast<const bf16x8*>(&Pl[wave][(mi * 16 + lo) * 40 + hi * 8]);
          __builtin_amdgcn_s_setprio(1);
#pragma unroll
          for (int f = 0; f < 8; ++f) {
            int d = f * 16 + lo;
            int cc = ((ks << 2) | hi) ^ (d & 7);
            bf16x8 vb = *reinterpret_cast<const bf16x8*>(&Vs[cur][d * 64 + cc * 8]);
#pragma unroll
            for (int mi = 0; mi < 2; ++mi)
              o[mi][f] = __builtin_amdgcn_mfma_f32_16x16x32_bf16(pa[mi], vb, o[mi][f], 0, 0, 0);
          }
          __builtin_amdgcn_s_setprio(0);
        }
      }
      __syncthreads();   // drains prefetch vmcnt + guards buffer reuse
      cur ^= 1;
    }

    // epilogue: normalize (broadcast 1/l to O-layout) and store merged heads
    ushort_t* obase = ob + (size_t)(b * N_ + q0w) * 2048 + h * 128;
#pragma unroll
    for (int mi = 0; mi < 2; ++mi) {
      float invl = 1.0f / l[mi];
      int bsrc = (lane & 48) | (hi << 2);
      float ib[4];
#pragma unroll
      for (int r = 0; r < 4; ++r) ib[r] = __shfl(invl, bsrc + r, 64);
#pragma unroll
      for (int f = 0; f < 8; ++f)
#pragma unroll
        for (int r = 0; r < 4; ++r)
          obase[(size_t)(mi * 16 + hi * 4 + r) * 2048 + f * 16 + lo] = f2bf(o[mi][f][r] * ib[r]);
    }
  }
}

extern "C" void kernel_launch(void* const* d_in, const int* in_sizes, int n_in,
                              void* d_out, int out_size, void* d_ws, size_t ws_size,
                              hipStream_t stream) {
  const float* x  = (const float*)d_in[0];
  const float* Wq = (const float*)d_in[1];
  const float* Wk = (const float*)d_in[2];
  const float* Wv = (const float*)d_in[3];
  const float* Wo = (const float*)d_in[4];
  float* out = (float*)d_out;

  // ws layout (bf16 elements). obuf aliases xb (dead after GEMM1);
  // vtg aliases w1t (dead after GEMM1, 4.2M <= 6.3M elems).
  ushort_t* xb   = (ushort_t*)d_ws;          // 8192*2048  = 16,777,216
  ushort_t* w1t  = xb  + 16777216;           // 3072*2048  =  6,291,456 (Wq^T|Wk^T|Wv^T)
  ushort_t* wot  = w1t + 6291456;            // 2048*2048  =  4,194,304
  ushort_t* qkv  = wot + 4194304;            // 8192*3072  = 25,165,824
  ushort_t* obuf = xb;                       // alias
  ushort_t* vtg  = w1t;                      // alias: 16*128*2048 = 4,194,304

  cvt_f32_bf16_k<<<16384, 256, 0, stream>>>(x, xb, 16777216);
  dim3 tb(32, 8);
  tconv_k<<<dim3(64, 64), tb, 0, stream>>>(Wq, w1t,               2048, 2048);
  tconv_k<<<dim3(16, 64), tb, 0, stream>>>(Wk, w1t + 2048 * 2048, 2048, 512);
  tconv_k<<<dim3(16, 64), tb, 0, stream>>>(Wv, w1t + 2560 * 2048, 2048, 512);
  tconv_k<<<dim3(64, 64), tb, 0, stream>>>(Wo, wot,               2048, 2048);

  // QKV projection: (8192 x 2048) * (3072 x 2048)^T -> bf16 qkv
  gemm_bt_k<0><<<dim3(24, 64), 256, 0, stream>>>(xb, w1t, qkv, 8192, 3072, 2048);
  // V^T for attention (w1t dead now)
  vt_k<<<dim3(64, 4, 16), tb, 0, stream>>>(qkv, vtg);
  // causal GQA flash attention (paired q-tiles: equal-work blocks)
  attn_k<<<dim3(8, 64), 256, 0, stream>>>(qkv, vtg, obuf);
  // output projection: (8192 x 2048) * (2048 x 2048)^T -> f32 out
  gemm_bt_k<1><<<dim3(16, 64), 256, 0, stream>>>(obuf, wot, out, 8192, 2048, 2048);
}